// Round 12
// baseline (316.146 us; speedup 1.0000x reference)
//
#include <hip/hip_runtime.h>
#include <stdint.h>

#define D_DIM 1024
#define NA_DIM 4096
#define NV_DIM 4096

typedef __bf16 bf16_t;
typedef __bf16 bf16x4 __attribute__((ext_vector_type(4)));
typedef __bf16 bf16x8 __attribute__((ext_vector_type(8)));
typedef float f32x4 __attribute__((ext_vector_type(4)));

// async global->LDS, 16B per lane; LDS base must be wave-uniform (HW adds lane*16)
__device__ __forceinline__ void gload_lds16(const void* g, void* lds) {
  __builtin_amdgcn_global_load_lds(
      (const __attribute__((address_space(1))) unsigned int*)g,
      (__attribute__((address_space(3))) unsigned int*)lds, 16, 0, 0);
}

// ====== 256x256 GEMM core (r11 "loose" structure - best-equal of 4 probed schedules) ======
// C[m][n] = sum_k A[m][k]*B[n][k]. 512 threads = 8 waves (2M x 4N), per-wave 128x64 via
// 8x4 mfma_f32_16x16x32_bf16 frags. BK=64/tile. LDS 128 KiB = 2 buf x {A,B}. T2 swizzle
// (16B chunk ^= row&7, both sides): SQ_LDS_BANK_CONFLICT = 0 (r2-r11).
// NOTE (r6-r11 post-mortems): 4 schedule variants {16-MFMA bunched, 32-MFMA bunched,
// counted-lgkm pipelined, fence-free loose} all land at ~5100 cyc/tile (MfmaUtil ~41%,
// ~1030 TF). Schedule-space derivative is zero at this geometry; core frozen.
#define VMW(N) asm volatile("s_waitcnt vmcnt(" #N ")" ::: "memory")
#define LKW(N) asm volatile("s_waitcnt lgkmcnt(" #N ")" ::: "memory")
#define BAR() asm volatile("s_barrier" ::: "memory")

__device__ __forceinline__ void gemm256_loose(const bf16_t* __restrict__ A,
                                              const bf16_t* __restrict__ B,
                                              int K, int kb, int klen, int bm, int bn,
                                              bf16_t* lds, f32x4 acc[8][4]) {
  const int tid = threadIdx.x;
  const int lane = tid & 63;
  const int wid = tid >> 6;
  const int wm = wid >> 2;   // 0..1 : wave row-half (128 rows)
  const int wn = wid & 3;    // 0..3 : wave col-quarter (64 cols)
  const int frow = lane & 15;
  const int hi = lane >> 4;
  const int k0e = ((hi ^ (frow & 7)) << 3);   // swizzled k-chunk (elems); ks=1: ^32

  // staging source (pre-swizzled): lane -> row (lane>>3), logical chunk (lane&7)^(lane>>3)
  const int sr = (wid << 4) + (lane >> 3);              // 0..127 within half-tile
  const int sc = (((lane & 7) ^ (lane >> 3)) << 3);     // source col elems within 64
  const bf16_t* pAs = A + (size_t)(bm + sr) * K + kb + sc;
  const bf16_t* pBs = B + (size_t)(bn + sr) * K + kb + sc;
  const int dstW = wid << 10;                            // wave's 1024-elem LDS stripe

  // fragment read bases (elems): + buf*32768; A half = wm, B half = wn>>1 (+ (wn&1)*64 rows)
  const int aBase = (wm << 13) + frow * 64 + k0e;
  const int bBase = 16384 + ((wn >> 1) << 13) + ((wn & 1) << 12) + frow * 64 + k0e;

#define STG_A(kt, h, bufb) do { \
    const bf16_t* s_ = pAs + (size_t)((h) * 128) * K + (size_t)(kt) * 64; \
    bf16_t* d_ = lds + (bufb) * 32768 + (h) * 8192 + dstW; \
    gload_lds16(s_, d_); gload_lds16(s_ + (size_t)8 * K, d_ + 512); } while (0)
#define STG_B(kt, h, bufb) do { \
    const bf16_t* s_ = pBs + (size_t)((h) * 128) * K + (size_t)(kt) * 64; \
    bf16_t* d_ = lds + (bufb) * 32768 + 16384 + (h) * 8192 + dstW; \
    gload_lds16(s_, d_); gload_lds16(s_ + (size_t)8 * K, d_ + 512); } while (0)

#define MFMA(a, b, c) __builtin_amdgcn_mfma_f32_16x16x32_bf16((a), (b), (c), 0, 0, 0)

#define TILE(P, T) do { \
    if ((T) + 1 < NT) { \
      STG_A((T) + 1, 0, (P) ^ 1); STG_A((T) + 1, 1, (P) ^ 1); \
      STG_B((T) + 1, 0, (P) ^ 1); STG_B((T) + 1, 1, (P) ^ 1); \
    } \
    { \
      const bf16_t* Lb_ = lds + (P) * 32768; \
      bf16x8 bf0[4], bf1[4]; \
      _Pragma("unroll") for (int fc = 0; fc < 4; ++fc) { \
        bf0[fc] = *(const bf16x8*)&Lb_[bBase + fc * 1024]; \
        bf1[fc] = *(const bf16x8*)&Lb_[(bBase ^ 32) + fc * 1024]; \
      } \
      _Pragma("unroll") for (int q = 0; q < 4; ++q) { \
        bf16x8 a0 = *(const bf16x8*)&Lb_[aBase + q * 2048]; \
        bf16x8 a1 = *(const bf16x8*)&Lb_[(aBase ^ 32) + q * 2048]; \
        bf16x8 a2 = *(const bf16x8*)&Lb_[aBase + q * 2048 + 1024]; \
        bf16x8 a3 = *(const bf16x8*)&Lb_[(aBase ^ 32) + q * 2048 + 1024]; \
        _Pragma("unroll") for (int fc = 0; fc < 4; ++fc) { \
          acc[q * 2][fc]     = MFMA(a0, bf0[fc], acc[q * 2][fc]); \
          acc[q * 2][fc]     = MFMA(a1, bf1[fc], acc[q * 2][fc]); \
          acc[q * 2 + 1][fc] = MFMA(a2, bf0[fc], acc[q * 2 + 1][fc]); \
          acc[q * 2 + 1][fc] = MFMA(a3, bf1[fc], acc[q * 2 + 1][fc]); \
        } \
      } \
    } \
    LKW(0); VMW(0); BAR(); \
  } while (0)

  const int NT = klen >> 6;   // BK=64 tiles (>= 16, even)

  STG_A(0, 0, 0); STG_A(0, 1, 0); STG_B(0, 0, 0); STG_B(0, 1, 0);
  VMW(0);
  BAR();

  for (int it = 0; it < (NT >> 1); ++it) {
    TILE(0, 2 * it);
    TILE(1, 2 * it + 1);
  }
#undef TILE
#undef MFMA
#undef STG_A
#undef STG_B
}

// epilogue: verified C/D map: col = lane&15, row = (lane>>4)*4 + reg
template <int BF16OUT>
__device__ __forceinline__ void store256(void* Cv, int ldc, int bm, int bn, f32x4 acc[8][4]) {
  const int lane = threadIdx.x & 63;
  const int wid = threadIdx.x >> 6;
  const int wm = wid >> 2, wn = wid & 3;
  const int frow = lane & 15, hi = lane >> 4;
  const int row0 = bm + wm * 128 + hi * 4;
  const int col0 = bn + wn * 64 + frow;
#pragma unroll
  for (int rf = 0; rf < 8; ++rf)
#pragma unroll
    for (int fc = 0; fc < 4; ++fc)
#pragma unroll
      for (int r = 0; r < 4; ++r) {
        size_t idx = (size_t)(row0 + rf * 16 + r) * ldc + (col0 + fc * 16);
        if constexpr (BF16OUT) ((bf16_t*)Cv)[idx] = (bf16_t)acc[rf][fc][r];
        else ((float*)Cv)[idx] = acc[rf][fc][r];
      }
}

// transposed store: CT[o][i] = C[i][o]; per frag the 4 reg rows are 4 consecutive i
// -> one bf16x4 (8B) store; lanes hi=0..3 cover i+{0,4,8,12} -> 32B segments per o-row.
__device__ __forceinline__ void store256T(bf16_t* CT, int ldcT, int bm, int bn, f32x4 acc[8][4]) {
  const int lane = threadIdx.x & 63;
  const int wid = threadIdx.x >> 6;
  const int wm = wid >> 2, wn = wid & 3;
  const int frow = lane & 15, hi = lane >> 4;
  const int row0 = bm + wm * 128 + hi * 4;   // i base
  const int col0 = bn + wn * 64 + frow;      // o base
#pragma unroll
  for (int rf = 0; rf < 8; ++rf)
#pragma unroll
    for (int fc = 0; fc < 4; ++fc) {
      bf16x4 v;
#pragma unroll
      for (int r = 0; r < 4; ++r) v[r] = (bf16_t)acc[rf][fc][r];
      *(bf16x4*)(&CT[(size_t)(col0 + fc * 16) * ldcT + row0 + rf * 16]) = v;
    }
}

// ---------------- batched projections; z=1,3 write TRANSPOSED (a_aT, b_vT) ----------
__global__ __launch_bounds__(512, 1) void gemm_proj4(
    const bf16_t* __restrict__ Xa, const bf16_t* __restrict__ Xv,
    const bf16_t* __restrict__ W0, const bf16_t* __restrict__ W1,
    const bf16_t* __restrict__ W2, const bf16_t* __restrict__ W3,
    bf16_t* __restrict__ C0, bf16_t* __restrict__ C1T,
    bf16_t* __restrict__ C2, bf16_t* __restrict__ C3T) {
  __shared__ bf16_t lds[65536];
  const int z = blockIdx.z;
  const bf16_t* A = (z < 2) ? Xa : Xv;
  const bf16_t* B = (z == 0) ? W0 : (z == 1) ? W1 : (z == 2) ? W2 : W3;
  f32x4 acc[8][4] = {};
  const int bm = blockIdx.x * 256, bn = blockIdx.y * 256;
  gemm256_loose(A, B, D_DIM, 0, D_DIM, bm, bn, lds, acc);
  if (z == 0) store256<1>(C0, D_DIM, bm, bn, acc);
  else if (z == 1) store256T(C1T, NA_DIM, bm, bn, acc);
  else if (z == 2) store256<1>(C2, D_DIM, bm, bn, acc);
  else store256T(C3T, NV_DIM, bm, bn, acc);
}

// ---------------- scores GEMM: [4096,1024]x[4096,1024]^T -> f32 ----------------
__global__ __launch_bounds__(512, 1) void gemm_scores(const bf16_t* __restrict__ A,
                                                      const bf16_t* __restrict__ B,
                                                      float* __restrict__ C) {
  __shared__ bf16_t lds[65536];
  f32x4 acc[8][4] = {};
  gemm256_loose(A, B, D_DIM, 0, D_DIM, blockIdx.x * 256, blockIdx.y * 256, lds, acc);
  store256<0>(C, NV_DIM, blockIdx.x * 256, blockIdx.y * 256, acc);
}

// ------- stage 4/5 split-K with TICKET-FUSED reduce + residual (no reduce pass) -------
// Each block writes its f32 partial, device-fence, atomicAdd ticket. Second arriver
// (atomic total order) reads the OTHER partial + residual, adds its own acc from
// REGISTERS, writes out. out = (P_other + acc_mine) + res: IEEE '+' commutative ->
// bit-identical regardless of arrival order (deterministic). No spin, no residency
// assumption (G16-safe: threadfence + device-scope atomic).
__global__ __launch_bounds__(512, 1) void gemm_splitk(
    const bf16_t* __restrict__ alpha, const bf16_t* __restrict__ bvT,
    const bf16_t* __restrict__ alphaT, const bf16_t* __restrict__ aaT,
    float* __restrict__ P, unsigned* __restrict__ ticket,
    const float* __restrict__ resA, const float* __restrict__ resV,
    float* __restrict__ out) {
  __shared__ bf16_t lds[65536];
  __shared__ unsigned tkOld;
  const int z = blockIdx.z;
  const bf16_t* A = (z < 2) ? alpha : alphaT;
  const bf16_t* B = (z < 2) ? bvT : aaT;
  const int kb = (z & 1) * 2048;
  const int bm = blockIdx.x * 256, bn = blockIdx.y * 256;
  f32x4 acc[8][4] = {};
  gemm256_loose(A, B, 4096, kb, 2048, bm, bn, lds, acc);

  store256<0>(P + (size_t)z * NA_DIM * D_DIM, D_DIM, bm, bn, acc);
  __threadfence();  // release my partial (device scope, cross-XCD)
  if (threadIdx.x == 0)
    tkOld = atomicAdd(&ticket[(z >> 1) * 64 + blockIdx.x * 4 + blockIdx.y], 1u);
  __syncthreads();
  if (tkOld == 1u) {  // I'm second: other's partial is visible (fence before its atomic)
    __threadfence();  // acquire
    const float* other = P + (size_t)(z ^ 1) * NA_DIM * D_DIM;
    const float* res = (z >> 1) ? resV : resA;
    float* o = out + (size_t)(z >> 1) * NA_DIM * D_DIM;
    const int lane = threadIdx.x & 63;
    const int wid = threadIdx.x >> 6;
    const int wm = wid >> 2, wn = wid & 3;
    const int frow = lane & 15, hi = lane >> 4;
    const int row0 = bm + wm * 128 + hi * 4;
    const int col0 = bn + wn * 64 + frow;
#pragma unroll
    for (int rf = 0; rf < 8; ++rf)
#pragma unroll
      for (int fc = 0; fc < 4; ++fc)
#pragma unroll
        for (int r = 0; r < 4; ++r) {
          size_t idx = (size_t)(row0 + rf * 16 + r) * D_DIM + (col0 + fc * 16);
          o[idx] = (other[idx] + acc[rf][fc][r]) + res[idx];
        }
  }
}

// ---------------- ticket zeroing (runs every replay, before splitk) ----------------
__global__ void zero_tickets(unsigned* __restrict__ t) { t[threadIdx.x] = 0u; }

// ---------------- f32 -> bf16 converts (batched) ----------------
__device__ __forceinline__ void cvt8(const float* in, bf16_t* out, int i) {
  float4 v0 = *(const float4*)(in + i);
  float4 v1 = *(const float4*)(in + i + 4);
  bf16x8 o;
  o[0] = (bf16_t)v0.x; o[1] = (bf16_t)v0.y; o[2] = (bf16_t)v0.z; o[3] = (bf16_t)v0.w;
  o[4] = (bf16_t)v1.x; o[5] = (bf16_t)v1.y; o[6] = (bf16_t)v1.z; o[7] = (bf16_t)v1.w;
  *(bf16x8*)(out + i) = o;
}

__global__ __launch_bounds__(256) void cvt2(const float* __restrict__ inA,
                                            const float* __restrict__ inV,
                                            bf16_t* __restrict__ oA,
                                            bf16_t* __restrict__ oV) {
  const float* in = blockIdx.y ? inV : inA;
  bf16_t* out = blockIdx.y ? oV : oA;
  cvt8(in, out, (blockIdx.x * 256 + threadIdx.x) * 8);
}

__global__ __launch_bounds__(256) void cvt4(const float* __restrict__ i0, const float* __restrict__ i1,
                                            const float* __restrict__ i2, const float* __restrict__ i3,
                                            bf16_t* __restrict__ o0, bf16_t* __restrict__ o1,
                                            bf16_t* __restrict__ o2, bf16_t* __restrict__ o3) {
  const int z = blockIdx.y;
  const float* in = (z == 0) ? i0 : (z == 1) ? i1 : (z == 2) ? i2 : i3;
  bf16_t* out = (z == 0) ? o0 : (z == 1) ? o1 : (z == 2) ? o2 : o3;
  cvt8(in, out, (blockIdx.x * 256 + threadIdx.x) * 8);
}

// ---------------- row softmax: f32 [rows][4096] -> bf16 alpha ----------------
__global__ __launch_bounds__(256) void softmax_rows(const float* __restrict__ S,
                                                    bf16_t* __restrict__ P) {
  const int row = blockIdx.x;
  const int ncol = 4096;
  const float* s = S + (size_t)row * ncol;
  const int base = threadIdx.x * 16;
  float v[16];
  float4* vp = (float4*)v;
#pragma unroll
  for (int q = 0; q < 4; ++q) vp[q] = *(const float4*)(s + base + q * 4);
  float m = v[0];
#pragma unroll
  for (int q = 1; q < 16; ++q) m = fmaxf(m, v[q]);
  for (int off = 32; off; off >>= 1) m = fmaxf(m, __shfl_xor(m, off));
  __shared__ float sm[4], ss[4];
  const int wid = threadIdx.x >> 6, lane = threadIdx.x & 63;
  if (lane == 0) sm[wid] = m;
  __syncthreads();
  m = fmaxf(fmaxf(sm[0], sm[1]), fmaxf(sm[2], sm[3]));
  float sum = 0.f;
#pragma unroll
  for (int q = 0; q < 16; ++q) { v[q] = __expf(v[q] - m); sum += v[q]; }
  for (int off = 32; off; off >>= 1) sum += __shfl_xor(sum, off);
  if (lane == 0) ss[wid] = sum;
  __syncthreads();
  const float inv = 1.0f / (ss[0] + ss[1] + ss[2] + ss[3]);
  bf16x8 o0, o1;
#pragma unroll
  for (int q = 0; q < 8; ++q) { o0[q] = (bf16_t)(v[q] * inv); o1[q] = (bf16_t)(v[q + 8] * inv); }
  bf16_t* p = P + (size_t)row * ncol + base;
  *(bf16x8*)p = o0;
  *(bf16x8*)(p + 8) = o1;
}

// ---------------- bf16 transpose: in[R][C] -> out[C][R], 64x64 LDS tiles ----------------
__global__ __launch_bounds__(256) void transpose_bf16(const bf16_t* __restrict__ in,
                                                      bf16_t* __restrict__ out, int R, int C) {
  __shared__ bf16_t t[64][72];
  const int bx = blockIdx.x * 64;
  const int by = blockIdx.y * 64;
  const int tid = threadIdx.x;
  const int c8 = (tid & 7) * 8;
  const int r = tid >> 3;
#pragma unroll
  for (int rr = 0; rr < 64; rr += 32) {
    bf16x8 v = *(const bf16x8*)(in + (size_t)(by + r + rr) * C + bx + c8);
    *(bf16x8*)&t[r + rr][c8] = v;
  }
  __syncthreads();
#pragma unroll
  for (int rr = 0; rr < 64; rr += 32) {
    bf16x8 v;
#pragma unroll
    for (int q = 0; q < 8; ++q) v[q] = t[c8 + q][r + rr];
    *(bf16x8*)(out + (size_t)(bx + r + rr) * R + by + c8) = v;
  }
}

extern "C" void kernel_launch(void* const* d_in, const int* in_sizes, int n_in,
                              void* d_out, int out_size, void* d_ws, size_t ws_size,
                              hipStream_t stream) {
  (void)in_sizes; (void)n_in; (void)out_size; (void)ws_size;
  const float* inA = (const float*)d_in[0];
  const float* inV = (const float*)d_in[1];
  const float* wBa = (const float*)d_in[2];
  const float* wAa = (const float*)d_in[3];
  const float* wBv = (const float*)d_in[4];
  const float* wAv = (const float*)d_in[5];
  float* out = (float*)d_out;

  // workspace layout (~170 MB; split-K partials alias the dead scores buffer)
  char* w = (char*)d_ws;
  auto take = [&](size_t bytes) { void* p = (void*)w; w += bytes; return p; };
  const size_t XB = (size_t)NA_DIM * D_DIM * 2;   // 8 MB
  const size_t WB = (size_t)D_DIM * D_DIM * 2;    // 2 MB
  bf16_t* XaB = (bf16_t*)take(XB);
  bf16_t* XvB = (bf16_t*)take(XB);
  bf16_t* WBaB = (bf16_t*)take(WB);
  bf16_t* WAaB = (bf16_t*)take(WB);
  bf16_t* WBvB = (bf16_t*)take(WB);
  bf16_t* WAvB = (bf16_t*)take(WB);
  bf16_t* b_a = (bf16_t*)take(XB);
  bf16_t* a_v = (bf16_t*)take(XB);
  bf16_t* a_aT = (bf16_t*)take(XB);   // [1024][4096], written directly by proj4 z=1
  bf16_t* b_vT = (bf16_t*)take(XB);   // [1024][4096], written directly by proj4 z=3
  float* scores = (float*)take((size_t)NA_DIM * NV_DIM * 4);   // 64 MB (reused for partials)
  bf16_t* alpha = (bf16_t*)take((size_t)NA_DIM * NV_DIM * 2);  // 32 MB
  bf16_t* alphaT = (bf16_t*)take((size_t)NA_DIM * NV_DIM * 2); // 32 MB
  unsigned* tickets = (unsigned*)take(1024);                   // 128 used
  float* P = scores;  // split-K partials (4 x 16 MB), alias: scores dead after softmax

  // zero tickets (every replay) + converts
  zero_tickets<<<1, 128, 0, stream>>>(tickets);
  cvt2<<<dim3(NA_DIM * D_DIM / 2048, 2), 256, 0, stream>>>(inA, inV, XaB, XvB);
  cvt4<<<dim3(D_DIM * D_DIM / 2048, 4), 256, 0, stream>>>(wBa, wAa, wAv, wBv,
                                                          WBaB, WAaB, WAvB, WBvB);

  // stage 1: 4 projections; z=1 -> a_aT (transposed store), z=3 -> b_vT (transposed)
  gemm_proj4<<<dim3(NA_DIM / 256, D_DIM / 256, 4), 512, 0, stream>>>(
      XaB, XvB, WBaB, WAaB, WAvB, WBvB, b_a, a_aT, a_v, b_vT);

  // stage 2: scores[i][j] = sum_k b_a[i][k] * a_v[j][k]
  gemm_scores<<<dim3(NA_DIM / 256, NV_DIM / 256), 512, 0, stream>>>(b_a, a_v, scores);

  // stage 3: row softmax -> bf16 alpha
  softmax_rows<<<NA_DIM, 256, 0, stream>>>(scores, alpha);

  // alpha transpose (only remaining transpose)
  transpose_bf16<<<dim3(NV_DIM / 64, NA_DIM / 64), 256, 0, stream>>>(alpha, alphaT, NA_DIM, NV_DIM);

  // stages 4+5: split-K=2 with ticket-fused reduce + residual (no separate reduce pass)
  gemm_splitk<<<dim3(NA_DIM / 256, D_DIM / 256, 4), 512, 0, stream>>>(
      alpha, b_vT, alphaT, a_aT, P, tickets, inA, inV, out);
}

// Round 13
// 200.710 us; speedup vs baseline: 1.5751x; 1.5751x over previous
//
#include <hip/hip_runtime.h>
#include <stdint.h>

#define D_DIM 1024
#define NA_DIM 4096
#define NV_DIM 4096

typedef __bf16 bf16_t;
typedef __bf16 bf16x4 __attribute__((ext_vector_type(4)));
typedef __bf16 bf16x8 __attribute__((ext_vector_type(8)));
typedef float f32x4 __attribute__((ext_vector_type(4)));

// async global->LDS, 16B per lane; LDS base must be wave-uniform (HW adds lane*16)
__device__ __forceinline__ void gload_lds16(const void* g, void* lds) {
  __builtin_amdgcn_global_load_lds(
      (const __attribute__((address_space(1))) unsigned int*)g,
      (__attribute__((address_space(3))) unsigned int*)lds, 16, 0, 0);
}

// ====== 256x256 GEMM core (r11 "loose" structure - best-equal of 4 probed schedules) ======
// C[m][n] = sum_k A[m][k]*B[n][k]. 512 threads = 8 waves (2M x 4N), per-wave 128x64 via
// 8x4 mfma_f32_16x16x32_bf16 frags. BK=64/tile. LDS 128 KiB = 2 buf x {A,B}. T2 swizzle
// (16B chunk ^= row&7, both sides): SQ_LDS_BANK_CONFLICT = 0 (r2-r12).
// r6-r11: 4 schedule variants all land ~5100 cyc/tile (MfmaUtil ~41%); core frozen.
// r12 LESSON: ticket-fused cross-block reduce requires device-scope __threadfence =
// L2 writeback on non-coherent-L2 XCDs -> 256 serialized flushes, 3x regression.
// Cross-block combining on this arch goes through a separate streaming pass.
#define VMW(N) asm volatile("s_waitcnt vmcnt(" #N ")" ::: "memory")
#define LKW(N) asm volatile("s_waitcnt lgkmcnt(" #N ")" ::: "memory")
#define BAR() asm volatile("s_barrier" ::: "memory")

__device__ __forceinline__ void gemm256_loose(const bf16_t* __restrict__ A,
                                              const bf16_t* __restrict__ B,
                                              int K, int kb, int klen, int bm, int bn,
                                              bf16_t* lds, f32x4 acc[8][4]) {
  const int tid = threadIdx.x;
  const int lane = tid & 63;
  const int wid = tid >> 6;
  const int wm = wid >> 2;   // 0..1 : wave row-half (128 rows)
  const int wn = wid & 3;    // 0..3 : wave col-quarter (64 cols)
  const int frow = lane & 15;
  const int hi = lane >> 4;
  const int k0e = ((hi ^ (frow & 7)) << 3);   // swizzled k-chunk (elems); ks=1: ^32

  // staging source (pre-swizzled): lane -> row (lane>>3), logical chunk (lane&7)^(lane>>3)
  const int sr = (wid << 4) + (lane >> 3);              // 0..127 within half-tile
  const int sc = (((lane & 7) ^ (lane >> 3)) << 3);     // source col elems within 64
  const bf16_t* pAs = A + (size_t)(bm + sr) * K + kb + sc;
  const bf16_t* pBs = B + (size_t)(bn + sr) * K + kb + sc;
  const int dstW = wid << 10;                            // wave's 1024-elem LDS stripe

  // fragment read bases (elems): + buf*32768; A half = wm, B half = wn>>1 (+ (wn&1)*64 rows)
  const int aBase = (wm << 13) + frow * 64 + k0e;
  const int bBase = 16384 + ((wn >> 1) << 13) + ((wn & 1) << 12) + frow * 64 + k0e;

#define STG_A(kt, h, bufb) do { \
    const bf16_t* s_ = pAs + (size_t)((h) * 128) * K + (size_t)(kt) * 64; \
    bf16_t* d_ = lds + (bufb) * 32768 + (h) * 8192 + dstW; \
    gload_lds16(s_, d_); gload_lds16(s_ + (size_t)8 * K, d_ + 512); } while (0)
#define STG_B(kt, h, bufb) do { \
    const bf16_t* s_ = pBs + (size_t)((h) * 128) * K + (size_t)(kt) * 64; \
    bf16_t* d_ = lds + (bufb) * 32768 + 16384 + (h) * 8192 + dstW; \
    gload_lds16(s_, d_); gload_lds16(s_ + (size_t)8 * K, d_ + 512); } while (0)

#define MFMA(a, b, c) __builtin_amdgcn_mfma_f32_16x16x32_bf16((a), (b), (c), 0, 0, 0)

#define TILE(P, T) do { \
    if ((T) + 1 < NT) { \
      STG_A((T) + 1, 0, (P) ^ 1); STG_A((T) + 1, 1, (P) ^ 1); \
      STG_B((T) + 1, 0, (P) ^ 1); STG_B((T) + 1, 1, (P) ^ 1); \
    } \
    { \
      const bf16_t* Lb_ = lds + (P) * 32768; \
      bf16x8 bf0[4], bf1[4]; \
      _Pragma("unroll") for (int fc = 0; fc < 4; ++fc) { \
        bf0[fc] = *(const bf16x8*)&Lb_[bBase + fc * 1024]; \
        bf1[fc] = *(const bf16x8*)&Lb_[(bBase ^ 32) + fc * 1024]; \
      } \
      _Pragma("unroll") for (int q = 0; q < 4; ++q) { \
        bf16x8 a0 = *(const bf16x8*)&Lb_[aBase + q * 2048]; \
        bf16x8 a1 = *(const bf16x8*)&Lb_[(aBase ^ 32) + q * 2048]; \
        bf16x8 a2 = *(const bf16x8*)&Lb_[aBase + q * 2048 + 1024]; \
        bf16x8 a3 = *(const bf16x8*)&Lb_[(aBase ^ 32) + q * 2048 + 1024]; \
        _Pragma("unroll") for (int fc = 0; fc < 4; ++fc) { \
          acc[q * 2][fc]     = MFMA(a0, bf0[fc], acc[q * 2][fc]); \
          acc[q * 2][fc]     = MFMA(a1, bf1[fc], acc[q * 2][fc]); \
          acc[q * 2 + 1][fc] = MFMA(a2, bf0[fc], acc[q * 2 + 1][fc]); \
          acc[q * 2 + 1][fc] = MFMA(a3, bf1[fc], acc[q * 2 + 1][fc]); \
        } \
      } \
    } \
    LKW(0); VMW(0); BAR(); \
  } while (0)

  const int NT = klen >> 6;   // BK=64 tiles (>= 16, even)

  STG_A(0, 0, 0); STG_A(0, 1, 0); STG_B(0, 0, 0); STG_B(0, 1, 0);
  VMW(0);
  BAR();

  for (int it = 0; it < (NT >> 1); ++it) {
    TILE(0, 2 * it);
    TILE(1, 2 * it + 1);
  }
#undef TILE
#undef MFMA
#undef STG_A
#undef STG_B
}

// epilogue: verified C/D map: col = lane&15, row = (lane>>4)*4 + reg
template <int BF16OUT>
__device__ __forceinline__ void store256(void* Cv, int ldc, int bm, int bn, f32x4 acc[8][4]) {
  const int lane = threadIdx.x & 63;
  const int wid = threadIdx.x >> 6;
  const int wm = wid >> 2, wn = wid & 3;
  const int frow = lane & 15, hi = lane >> 4;
  const int row0 = bm + wm * 128 + hi * 4;
  const int col0 = bn + wn * 64 + frow;
#pragma unroll
  for (int rf = 0; rf < 8; ++rf)
#pragma unroll
    for (int fc = 0; fc < 4; ++fc)
#pragma unroll
      for (int r = 0; r < 4; ++r) {
        size_t idx = (size_t)(row0 + rf * 16 + r) * ldc + (col0 + fc * 16);
        if constexpr (BF16OUT) ((bf16_t*)Cv)[idx] = (bf16_t)acc[rf][fc][r];
        else ((float*)Cv)[idx] = acc[rf][fc][r];
      }
}

// transposed store: CT[o][i] = C[i][o]; per frag the 4 reg rows are 4 consecutive i
// -> one bf16x4 (8B) store; lanes hi=0..3 cover i+{0,4,8,12} -> 32B segments per o-row.
__device__ __forceinline__ void store256T(bf16_t* CT, int ldcT, int bm, int bn, f32x4 acc[8][4]) {
  const int lane = threadIdx.x & 63;
  const int wid = threadIdx.x >> 6;
  const int wm = wid >> 2, wn = wid & 3;
  const int frow = lane & 15, hi = lane >> 4;
  const int row0 = bm + wm * 128 + hi * 4;   // i base
  const int col0 = bn + wn * 64 + frow;      // o base
#pragma unroll
  for (int rf = 0; rf < 8; ++rf)
#pragma unroll
    for (int fc = 0; fc < 4; ++fc) {
      bf16x4 v;
#pragma unroll
      for (int r = 0; r < 4; ++r) v[r] = (bf16_t)acc[rf][fc][r];
      *(bf16x4*)(&CT[(size_t)(col0 + fc * 16) * ldcT + row0 + rf * 16]) = v;
    }
}

// ---------------- batched projections; z=1,3 write TRANSPOSED (a_aT, b_vT) ----------
__global__ __launch_bounds__(512, 1) void gemm_proj4(
    const bf16_t* __restrict__ Xa, const bf16_t* __restrict__ Xv,
    const bf16_t* __restrict__ W0, const bf16_t* __restrict__ W1,
    const bf16_t* __restrict__ W2, const bf16_t* __restrict__ W3,
    bf16_t* __restrict__ C0, bf16_t* __restrict__ C1T,
    bf16_t* __restrict__ C2, bf16_t* __restrict__ C3T) {
  __shared__ bf16_t lds[65536];
  const int z = blockIdx.z;
  const bf16_t* A = (z < 2) ? Xa : Xv;
  const bf16_t* B = (z == 0) ? W0 : (z == 1) ? W1 : (z == 2) ? W2 : W3;
  f32x4 acc[8][4] = {};
  const int bm = blockIdx.x * 256, bn = blockIdx.y * 256;
  gemm256_loose(A, B, D_DIM, 0, D_DIM, bm, bn, lds, acc);
  if (z == 0) store256<1>(C0, D_DIM, bm, bn, acc);
  else if (z == 1) store256T(C1T, NA_DIM, bm, bn, acc);
  else if (z == 2) store256<1>(C2, D_DIM, bm, bn, acc);
  else store256T(C3T, NV_DIM, bm, bn, acc);
}

// ---------------- scores GEMM: [4096,1024]x[4096,1024]^T -> f32 ----------------
__global__ __launch_bounds__(512, 1) void gemm_scores(const bf16_t* __restrict__ A,
                                                      const bf16_t* __restrict__ B,
                                                      float* __restrict__ C) {
  __shared__ bf16_t lds[65536];
  f32x4 acc[8][4] = {};
  gemm256_loose(A, B, D_DIM, 0, D_DIM, blockIdx.x * 256, blockIdx.y * 256, lds, acc);
  store256<0>(C, NV_DIM, blockIdx.x * 256, blockIdx.y * 256, acc);
}

// ---------------- stage 4/5 batched split-K: z = gemm*2 + split ----------------
__global__ __launch_bounds__(512, 1) void gemm_splitk(
    const bf16_t* __restrict__ alpha, const bf16_t* __restrict__ bvT,
    const bf16_t* __restrict__ alphaT, const bf16_t* __restrict__ aaT,
    float* __restrict__ P) {
  __shared__ bf16_t lds[65536];
  const int z = blockIdx.z;
  const bf16_t* A = (z < 2) ? alpha : alphaT;
  const bf16_t* B = (z < 2) ? bvT : aaT;
  const int kb = (z & 1) * 2048;
  f32x4 acc[8][4] = {};
  gemm256_loose(A, B, 4096, kb, 2048, blockIdx.x * 256, blockIdx.y * 256, lds, acc);
  store256<0>(P + (size_t)z * NA_DIM * D_DIM, D_DIM, blockIdx.x * 256, blockIdx.y * 256, acc);
}

// ---------------- split-K reduce + residual add: out = P0 + P1 + res ----------------
__global__ __launch_bounds__(256) void reduce_splitk(const float* __restrict__ P,
                                                     const float* __restrict__ resA,
                                                     const float* __restrict__ resV,
                                                     float* __restrict__ out) {
  const int g = blockIdx.y;
  const size_t n = (size_t)NA_DIM * D_DIM;
  size_t i = ((size_t)blockIdx.x * 256 + threadIdx.x) * 4;
  const float* p0 = P + (size_t)g * 2 * n;
  const float* p1 = p0 + n;
  const float* r = g ? resV : resA;
  float4 a = *(const float4*)(p0 + i);
  float4 b = *(const float4*)(p1 + i);
  float4 c = *(const float4*)(r + i);
  float4 o = {a.x + b.x + c.x, a.y + b.y + c.y, a.z + b.z + c.z, a.w + b.w + c.w};
  *(float4*)(out + g * n + i) = o;
}

// ---------------- f32 -> bf16 converts (batched) ----------------
__device__ __forceinline__ void cvt8(const float* in, bf16_t* out, int i) {
  float4 v0 = *(const float4*)(in + i);
  float4 v1 = *(const float4*)(in + i + 4);
  bf16x8 o;
  o[0] = (bf16_t)v0.x; o[1] = (bf16_t)v0.y; o[2] = (bf16_t)v0.z; o[3] = (bf16_t)v0.w;
  o[4] = (bf16_t)v1.x; o[5] = (bf16_t)v1.y; o[6] = (bf16_t)v1.z; o[7] = (bf16_t)v1.w;
  *(bf16x8*)(out + i) = o;
}

__global__ __launch_bounds__(256) void cvt2(const float* __restrict__ inA,
                                            const float* __restrict__ inV,
                                            bf16_t* __restrict__ oA,
                                            bf16_t* __restrict__ oV) {
  const float* in = blockIdx.y ? inV : inA;
  bf16_t* out = blockIdx.y ? oV : oA;
  cvt8(in, out, (blockIdx.x * 256 + threadIdx.x) * 8);
}

__global__ __launch_bounds__(256) void cvt4(const float* __restrict__ i0, const float* __restrict__ i1,
                                            const float* __restrict__ i2, const float* __restrict__ i3,
                                            bf16_t* __restrict__ o0, bf16_t* __restrict__ o1,
                                            bf16_t* __restrict__ o2, bf16_t* __restrict__ o3) {
  const int z = blockIdx.y;
  const float* in = (z == 0) ? i0 : (z == 1) ? i1 : (z == 2) ? i2 : i3;
  bf16_t* out = (z == 0) ? o0 : (z == 1) ? o1 : (z == 2) ? o2 : o3;
  cvt8(in, out, (blockIdx.x * 256 + threadIdx.x) * 8);
}

// ---------------- row softmax: f32 [rows][4096] -> bf16 alpha ----------------
__global__ __launch_bounds__(256) void softmax_rows(const float* __restrict__ S,
                                                    bf16_t* __restrict__ P) {
  const int row = blockIdx.x;
  const int ncol = 4096;
  const float* s = S + (size_t)row * ncol;
  const int base = threadIdx.x * 16;
  float v[16];
  float4* vp = (float4*)v;
#pragma unroll
  for (int q = 0; q < 4; ++q) vp[q] = *(const float4*)(s + base + q * 4);
  float m = v[0];
#pragma unroll
  for (int q = 1; q < 16; ++q) m = fmaxf(m, v[q]);
  for (int off = 32; off; off >>= 1) m = fmaxf(m, __shfl_xor(m, off));
  __shared__ float sm[4], ss[4];
  const int wid = threadIdx.x >> 6, lane = threadIdx.x & 63;
  if (lane == 0) sm[wid] = m;
  __syncthreads();
  m = fmaxf(fmaxf(sm[0], sm[1]), fmaxf(sm[2], sm[3]));
  float sum = 0.f;
#pragma unroll
  for (int q = 0; q < 16; ++q) { v[q] = __expf(v[q] - m); sum += v[q]; }
  for (int off = 32; off; off >>= 1) sum += __shfl_xor(sum, off);
  if (lane == 0) ss[wid] = sum;
  __syncthreads();
  const float inv = 1.0f / (ss[0] + ss[1] + ss[2] + ss[3]);
  bf16x8 o0, o1;
#pragma unroll
  for (int q = 0; q < 8; ++q) { o0[q] = (bf16_t)(v[q] * inv); o1[q] = (bf16_t)(v[q + 8] * inv); }
  bf16_t* p = P + (size_t)row * ncol + base;
  *(bf16x8*)p = o0;
  *(bf16x8*)(p + 8) = o1;
}

// ---------------- bf16 transpose: in[R][C] -> out[C][R], 64x64 LDS tiles ----------------
__global__ __launch_bounds__(256) void transpose_bf16(const bf16_t* __restrict__ in,
                                                      bf16_t* __restrict__ out, int R, int C) {
  __shared__ bf16_t t[64][72];
  const int bx = blockIdx.x * 64;
  const int by = blockIdx.y * 64;
  const int tid = threadIdx.x;
  const int c8 = (tid & 7) * 8;
  const int r = tid >> 3;
#pragma unroll
  for (int rr = 0; rr < 64; rr += 32) {
    bf16x8 v = *(const bf16x8*)(in + (size_t)(by + r + rr) * C + bx + c8);
    *(bf16x8*)&t[r + rr][c8] = v;
  }
  __syncthreads();
#pragma unroll
  for (int rr = 0; rr < 64; rr += 32) {
    bf16x8 v;
#pragma unroll
    for (int q = 0; q < 8; ++q) v[q] = t[c8 + q][r + rr];
    *(bf16x8*)(out + (size_t)(bx + r + rr) * R + by + c8) = v;
  }
}

extern "C" void kernel_launch(void* const* d_in, const int* in_sizes, int n_in,
                              void* d_out, int out_size, void* d_ws, size_t ws_size,
                              hipStream_t stream) {
  (void)in_sizes; (void)n_in; (void)out_size; (void)ws_size;
  const float* inA = (const float*)d_in[0];
  const float* inV = (const float*)d_in[1];
  const float* wBa = (const float*)d_in[2];
  const float* wAa = (const float*)d_in[3];
  const float* wBv = (const float*)d_in[4];
  const float* wAv = (const float*)d_in[5];
  float* out = (float*)d_out;

  // workspace layout (~170 MB; split-K partials alias the dead scores buffer)
  char* w = (char*)d_ws;
  auto take = [&](size_t bytes) { void* p = (void*)w; w += bytes; return p; };
  const size_t XB = (size_t)NA_DIM * D_DIM * 2;   // 8 MB
  const size_t WB = (size_t)D_DIM * D_DIM * 2;    // 2 MB
  bf16_t* XaB = (bf16_t*)take(XB);
  bf16_t* XvB = (bf16_t*)take(XB);
  bf16_t* WBaB = (bf16_t*)take(WB);
  bf16_t* WAaB = (bf16_t*)take(WB);
  bf16_t* WBvB = (bf16_t*)take(WB);
  bf16_t* WAvB = (bf16_t*)take(WB);
  bf16_t* b_a = (bf16_t*)take(XB);
  bf16_t* a_v = (bf16_t*)take(XB);
  bf16_t* a_aT = (bf16_t*)take(XB);   // [1024][4096], written directly by proj4 z=1
  bf16_t* b_vT = (bf16_t*)take(XB);   // [1024][4096], written directly by proj4 z=3
  float* scores = (float*)take((size_t)NA_DIM * NV_DIM * 4);   // 64 MB (reused for partials)
  bf16_t* alpha = (bf16_t*)take((size_t)NA_DIM * NV_DIM * 2);  // 32 MB
  bf16_t* alphaT = (bf16_t*)take((size_t)NA_DIM * NV_DIM * 2); // 32 MB
  float* P = scores;  // split-K partials (4 x 16 MB), alias: scores dead after softmax

  // converts
  cvt2<<<dim3(NA_DIM * D_DIM / 2048, 2), 256, 0, stream>>>(inA, inV, XaB, XvB);
  cvt4<<<dim3(D_DIM * D_DIM / 2048, 4), 256, 0, stream>>>(wBa, wAa, wAv, wBv,
                                                          WBaB, WAaB, WAvB, WBvB);

  // stage 1: 4 projections; z=1 -> a_aT (transposed store), z=3 -> b_vT (transposed)
  gemm_proj4<<<dim3(NA_DIM / 256, D_DIM / 256, 4), 512, 0, stream>>>(
      XaB, XvB, WBaB, WAaB, WAvB, WBvB, b_a, a_aT, a_v, b_vT);

  // stage 2: scores[i][j] = sum_k b_a[i][k] * a_v[j][k]
  gemm_scores<<<dim3(NA_DIM / 256, NV_DIM / 256), 512, 0, stream>>>(b_a, a_v, scores);

  // stage 3: row softmax -> bf16 alpha
  softmax_rows<<<NA_DIM, 256, 0, stream>>>(scores, alpha);

  // alpha transpose (only remaining transpose)
  transpose_bf16<<<dim3(NV_DIM / 64, NA_DIM / 64), 256, 0, stream>>>(alpha, alphaT, NA_DIM, NV_DIM);

  // stages 4+5: batched split-K=2 (256 blocks), then reduce+residual
  gemm_splitk<<<dim3(NA_DIM / 256, D_DIM / 256, 4), 512, 0, stream>>>(
      alpha, b_vT, alphaT, a_aT, P);
  reduce_splitk<<<dim3(NA_DIM * D_DIM / 1024, 2), 256, 0, stream>>>(P, inA, inV, out);
}

// Round 15
// 191.205 us; speedup vs baseline: 1.6534x; 1.0497x over previous
//
#include <hip/hip_runtime.h>
#include <stdint.h>

#define D_DIM 1024
#define NA_DIM 4096
#define NV_DIM 4096

typedef __bf16 bf16_t;
typedef __bf16 bf16x4 __attribute__((ext_vector_type(4)));
typedef __bf16 bf16x8 __attribute__((ext_vector_type(8)));
typedef float f32x4 __attribute__((ext_vector_type(4)));

// async global->LDS, 16B per lane; LDS base must be wave-uniform (HW adds lane*16)
__device__ __forceinline__ void gload_lds16(const void* g, void* lds) {
  __builtin_amdgcn_global_load_lds(
      (const __attribute__((address_space(1))) unsigned int*)g,
      (__attribute__((address_space(3))) unsigned int*)lds, 16, 0, 0);
}

// ====== 256x256 GEMM core (r11 "loose" structure - best-equal of 4 probed schedules) ======
// C[m][n] = sum_k A[m][k]*B[n][k]. 512 threads = 8 waves (2M x 4N), per-wave 128x64 via
// 8x4 mfma_f32_16x16x32_bf16 frags. BK=64/tile. LDS 128 KiB = 2 buf x {A,B}. T2 swizzle
// (16B chunk ^= row&7, both sides): SQ_LDS_BANK_CONFLICT = 0 (r2-r13).
// r6-r11: 4 schedule variants all land ~5100 cyc/tile (MfmaUtil ~41%); core frozen.
// r12: ticket-fused reduce = device-fence L2 writeback storm on non-coherent XCDs; never again.
#define VMW(N) asm volatile("s_waitcnt vmcnt(" #N ")" ::: "memory")
#define LKW(N) asm volatile("s_waitcnt lgkmcnt(" #N ")" ::: "memory")
#define BAR() asm volatile("s_barrier" ::: "memory")

__device__ __forceinline__ void gemm256_loose(const bf16_t* __restrict__ A,
                                              const bf16_t* __restrict__ B,
                                              int K, int kb, int klen, int bm, int bn,
                                              bf16_t* lds, f32x4 acc[8][4]) {
  const int tid = threadIdx.x;
  const int lane = tid & 63;
  const int wid = tid >> 6;
  const int wm = wid >> 2;   // 0..1 : wave row-half (128 rows)
  const int wn = wid & 3;    // 0..3 : wave col-quarter (64 cols)
  const int frow = lane & 15;
  const int hi = lane >> 4;
  const int k0e = ((hi ^ (frow & 7)) << 3);   // swizzled k-chunk (elems); ks=1: ^32

  // staging source (pre-swizzled): lane -> row (lane>>3), logical chunk (lane&7)^(lane>>3)
  const int sr = (wid << 4) + (lane >> 3);              // 0..127 within half-tile
  const int sc = (((lane & 7) ^ (lane >> 3)) << 3);     // source col elems within 64
  const bf16_t* pAs = A + (size_t)(bm + sr) * K + kb + sc;
  const bf16_t* pBs = B + (size_t)(bn + sr) * K + kb + sc;
  const int dstW = wid << 10;                            // wave's 1024-elem LDS stripe

  const int aBase = (wm << 13) + frow * 64 + k0e;
  const int bBase = 16384 + ((wn >> 1) << 13) + ((wn & 1) << 12) + frow * 64 + k0e;

#define STG_A(kt, h, bufb) do { \
    const bf16_t* s_ = pAs + (size_t)((h) * 128) * K + (size_t)(kt) * 64; \
    bf16_t* d_ = lds + (bufb) * 32768 + (h) * 8192 + dstW; \
    gload_lds16(s_, d_); gload_lds16(s_ + (size_t)8 * K, d_ + 512); } while (0)
#define STG_B(kt, h, bufb) do { \
    const bf16_t* s_ = pBs + (size_t)((h) * 128) * K + (size_t)(kt) * 64; \
    bf16_t* d_ = lds + (bufb) * 32768 + 16384 + (h) * 8192 + dstW; \
    gload_lds16(s_, d_); gload_lds16(s_ + (size_t)8 * K, d_ + 512); } while (0)

#define MFMA(a, b, c) __builtin_amdgcn_mfma_f32_16x16x32_bf16((a), (b), (c), 0, 0, 0)

#define TILE(P, T) do { \
    if ((T) + 1 < NT) { \
      STG_A((T) + 1, 0, (P) ^ 1); STG_A((T) + 1, 1, (P) ^ 1); \
      STG_B((T) + 1, 0, (P) ^ 1); STG_B((T) + 1, 1, (P) ^ 1); \
    } \
    { \
      const bf16_t* Lb_ = lds + (P) * 32768; \
      bf16x8 bf0[4], bf1[4]; \
      _Pragma("unroll") for (int fc = 0; fc < 4; ++fc) { \
        bf0[fc] = *(const bf16x8*)&Lb_[bBase + fc * 1024]; \
        bf1[fc] = *(const bf16x8*)&Lb_[(bBase ^ 32) + fc * 1024]; \
      } \
      _Pragma("unroll") for (int q = 0; q < 4; ++q) { \
        bf16x8 a0 = *(const bf16x8*)&Lb_[aBase + q * 2048]; \
        bf16x8 a1 = *(const bf16x8*)&Lb_[(aBase ^ 32) + q * 2048]; \
        bf16x8 a2 = *(const bf16x8*)&Lb_[aBase + q * 2048 + 1024]; \
        bf16x8 a3 = *(const bf16x8*)&Lb_[(aBase ^ 32) + q * 2048 + 1024]; \
        _Pragma("unroll") for (int fc = 0; fc < 4; ++fc) { \
          acc[q * 2][fc]     = MFMA(a0, bf0[fc], acc[q * 2][fc]); \
          acc[q * 2][fc]     = MFMA(a1, bf1[fc], acc[q * 2][fc]); \
          acc[q * 2 + 1][fc] = MFMA(a2, bf0[fc], acc[q * 2 + 1][fc]); \
          acc[q * 2 + 1][fc] = MFMA(a3, bf1[fc], acc[q * 2 + 1][fc]); \
        } \
      } \
    } \
    LKW(0); VMW(0); BAR(); \
  } while (0)

  const int NT = klen >> 6;   // BK=64 tiles (>= 16, even)

  STG_A(0, 0, 0); STG_A(0, 1, 0); STG_B(0, 0, 0); STG_B(0, 1, 0);
  VMW(0);
  BAR();

  for (int it = 0; it < (NT >> 1); ++it) {
    TILE(0, 2 * it);
    TILE(1, 2 * it + 1);
  }
#undef TILE
#undef MFMA
#undef STG_A
#undef STG_B
}

// ====== 128x256 GEMM core, full-K, fused residual epilogue (stages 4/5) ======
// Same loose schedule / swizzle / staging macros, BM=128: A = one 128-row half-tile,
// B = two. LDS 96 KiB = 2 buf x (A 16KB + B 32KB). Per-wave output 64x64 (4x4 frags).
// Grid (32, 4, 2) = 256 blocks = 1/CU with FULL K=4096 -> no split-K partials, no
// reduce pass (r13: reduce ~21us + 128MB HBM), residual fused into epilogue.
__device__ __forceinline__ void gemm128_loose(const bf16_t* __restrict__ A,
                                              const bf16_t* __restrict__ B,
                                              int K, int bm, int bn,
                                              bf16_t* lds, f32x4 acc[4][4]) {
  const int tid = threadIdx.x;
  const int lane = tid & 63;
  const int wid = tid >> 6;
  const int wm = wid >> 2;   // 0..1 : wave row-half (64 rows)
  const int wn = wid & 3;    // 0..3 : wave col-quarter (64 cols)
  const int frow = lane & 15;
  const int hi = lane >> 4;
  const int k0e = ((hi ^ (frow & 7)) << 3);

  const int sr = (wid << 4) + (lane >> 3);
  const int sc = (((lane & 7) ^ (lane >> 3)) << 3);
  const bf16_t* pAs = A + (size_t)(bm + sr) * K + sc;
  const bf16_t* pBs = B + (size_t)(bn + sr) * K + sc;
  const int dstW = wid << 10;

  // LDS elems: buffer stride 24576 (48KB); A [128][64] at 0; B [256][64] at 8192.
  const int aBase = (wm << 12) + frow * 64 + k0e;            // wm*64 rows
  const int bBase = 8192 + (wn << 12) + frow * 64 + k0e;     // wn*64 rows

#define STG_A1(kt, bufb) do { \
    const bf16_t* s_ = pAs + (size_t)(kt) * 64; \
    bf16_t* d_ = lds + (bufb) * 24576 + dstW; \
    gload_lds16(s_, d_); gload_lds16(s_ + (size_t)8 * K, d_ + 512); } while (0)
#define STG_B1(kt, h, bufb) do { \
    const bf16_t* s_ = pBs + (size_t)((h) * 128) * K + (size_t)(kt) * 64; \
    bf16_t* d_ = lds + (bufb) * 24576 + 8192 + (h) * 8192 + dstW; \
    gload_lds16(s_, d_); gload_lds16(s_ + (size_t)8 * K, d_ + 512); } while (0)

#define MFMA(a, b, c) __builtin_amdgcn_mfma_f32_16x16x32_bf16((a), (b), (c), 0, 0, 0)

#define TILE1(P, T) do { \
    if ((T) + 1 < NT) { \
      STG_A1((T) + 1, (P) ^ 1); \
      STG_B1((T) + 1, 0, (P) ^ 1); STG_B1((T) + 1, 1, (P) ^ 1); \
    } \
    { \
      const bf16_t* Lb_ = lds + (P) * 24576; \
      bf16x8 bf0[4], bf1[4]; \
      _Pragma("unroll") for (int fc = 0; fc < 4; ++fc) { \
        bf0[fc] = *(const bf16x8*)&Lb_[bBase + fc * 1024]; \
        bf1[fc] = *(const bf16x8*)&Lb_[(bBase ^ 32) + fc * 1024]; \
      } \
      _Pragma("unroll") for (int q = 0; q < 4; ++q) { \
        bf16x8 a0 = *(const bf16x8*)&Lb_[aBase + q * 1024]; \
        bf16x8 a1 = *(const bf16x8*)&Lb_[(aBase ^ 32) + q * 1024]; \
        _Pragma("unroll") for (int fc = 0; fc < 4; ++fc) { \
          acc[q][fc] = MFMA(a0, bf0[fc], acc[q][fc]); \
          acc[q][fc] = MFMA(a1, bf1[fc], acc[q][fc]); \
        } \
      } \
    } \
    LKW(0); VMW(0); BAR(); \
  } while (0)

  const int NT = K >> 6;   // 64 tiles

  STG_A1(0, 0); STG_B1(0, 0, 0); STG_B1(0, 1, 0);
  VMW(0);
  BAR();

  for (int it = 0; it < (NT >> 1); ++it) {
    TILE1(0, 2 * it);
    TILE1(1, 2 * it + 1);
  }
#undef TILE1
#undef MFMA
#undef STG_A1
#undef STG_B1
}

// epilogue: verified C/D map: col = lane&15, row = (lane>>4)*4 + reg
template <int BF16OUT>
__device__ __forceinline__ void store256(void* Cv, int ldc, int bm, int bn, f32x4 acc[8][4]) {
  const int lane = threadIdx.x & 63;
  const int wid = threadIdx.x >> 6;
  const int wm = wid >> 2, wn = wid & 3;
  const int frow = lane & 15, hi = lane >> 4;
  const int row0 = bm + wm * 128 + hi * 4;
  const int col0 = bn + wn * 64 + frow;
#pragma unroll
  for (int rf = 0; rf < 8; ++rf)
#pragma unroll
    for (int fc = 0; fc < 4; ++fc)
#pragma unroll
      for (int r = 0; r < 4; ++r) {
        size_t idx = (size_t)(row0 + rf * 16 + r) * ldc + (col0 + fc * 16);
        if constexpr (BF16OUT) ((bf16_t*)Cv)[idx] = (bf16_t)acc[rf][fc][r];
        else ((float*)Cv)[idx] = acc[rf][fc][r];
      }
}

// transposed store: CT[o][i] = C[i][o]; per frag the 4 reg rows are 4 consecutive i
// -> one bf16x4 (8B) store; lanes hi=0..3 cover i+{0,4,8,12} -> 32B segments per o-row.
__device__ __forceinline__ void store256T(bf16_t* CT, int ldcT, int bm, int bn, f32x4 acc[8][4]) {
  const int lane = threadIdx.x & 63;
  const int wid = threadIdx.x >> 6;
  const int wm = wid >> 2, wn = wid & 3;
  const int frow = lane & 15, hi = lane >> 4;
  const int row0 = bm + wm * 128 + hi * 4;   // i base
  const int col0 = bn + wn * 64 + frow;      // o base
#pragma unroll
  for (int rf = 0; rf < 8; ++rf)
#pragma unroll
    for (int fc = 0; fc < 4; ++fc) {
      bf16x4 v;
#pragma unroll
      for (int r = 0; r < 4; ++r) v[r] = (bf16_t)acc[rf][fc][r];
      *(bf16x4*)(&CT[(size_t)(col0 + fc * 16) * ldcT + row0 + rf * 16]) = v;
    }
}

// ---------------- batched projections; z=1,3 write TRANSPOSED (a_aT, b_vT) ----------
__global__ __launch_bounds__(512, 1) void gemm_proj4(
    const bf16_t* __restrict__ Xa, const bf16_t* __restrict__ Xv,
    const bf16_t* __restrict__ W0, const bf16_t* __restrict__ W1,
    const bf16_t* __restrict__ W2, const bf16_t* __restrict__ W3,
    bf16_t* __restrict__ C0, bf16_t* __restrict__ C1T,
    bf16_t* __restrict__ C2, bf16_t* __restrict__ C3T) {
  __shared__ bf16_t lds[65536];
  const int z = blockIdx.z;
  const bf16_t* A = (z < 2) ? Xa : Xv;
  const bf16_t* B = (z == 0) ? W0 : (z == 1) ? W1 : (z == 2) ? W2 : W3;
  f32x4 acc[8][4] = {};
  const int bm = blockIdx.x * 256, bn = blockIdx.y * 256;
  gemm256_loose(A, B, D_DIM, 0, D_DIM, bm, bn, lds, acc);
  if (z == 0) store256<1>(C0, D_DIM, bm, bn, acc);
  else if (z == 1) store256T(C1T, NA_DIM, bm, bn, acc);
  else if (z == 2) store256<1>(C2, D_DIM, bm, bn, acc);
  else store256T(C3T, NV_DIM, bm, bn, acc);
}

// ---------------- scores GEMM: [4096,1024]x[4096,1024]^T -> f32 ----------------
__global__ __launch_bounds__(512, 1) void gemm_scores(const bf16_t* __restrict__ A,
                                                      const bf16_t* __restrict__ B,
                                                      float* __restrict__ C) {
  __shared__ bf16_t lds[65536];
  f32x4 acc[8][4] = {};
  gemm256_loose(A, B, D_DIM, 0, D_DIM, blockIdx.x * 256, blockIdx.y * 256, lds, acc);
  store256<0>(C, NV_DIM, blockIdx.x * 256, blockIdx.y * 256, acc);
}

// ------- stages 4/5: 128x256-tile, FULL K=4096, fused residual; no split-K -------
__global__ __launch_bounds__(512, 1) void gemm_att(
    const bf16_t* __restrict__ alpha, const bf16_t* __restrict__ bvT,
    const bf16_t* __restrict__ alphaT, const bf16_t* __restrict__ aaT,
    const float* __restrict__ resA, const float* __restrict__ resV,
    float* __restrict__ out) {
  __shared__ bf16_t lds[49152];  // 96 KiB
  const int z = blockIdx.z;
  const bf16_t* A = z ? alphaT : alpha;
  const bf16_t* B = z ? aaT : bvT;
  const float* res = z ? resV : resA;
  float* o = out + (size_t)z * NA_DIM * D_DIM;
  const int bm = blockIdx.x * 128, bn = blockIdx.y * 256;
  f32x4 acc[4][4] = {};
  gemm128_loose(A, B, 4096, bm, bn, lds, acc);

  const int lane = threadIdx.x & 63;
  const int wid = threadIdx.x >> 6;
  const int wm = wid >> 2, wn = wid & 3;
  const int frow = lane & 15, hi = lane >> 4;
  const int row0 = bm + wm * 64 + hi * 4;
  const int col0 = bn + wn * 64 + frow;
#pragma unroll
  for (int rf = 0; rf < 4; ++rf)
#pragma unroll
    for (int fc = 0; fc < 4; ++fc)
#pragma unroll
      for (int r = 0; r < 4; ++r) {
        size_t idx = (size_t)(row0 + rf * 16 + r) * D_DIM + (col0 + fc * 16);
        o[idx] = acc[rf][fc][r] + res[idx];
      }
}

// ---------------- f32 -> bf16 converts (batched) ----------------
__device__ __forceinline__ void cvt8(const float* in, bf16_t* out, int i) {
  float4 v0 = *(const float4*)(in + i);
  float4 v1 = *(const float4*)(in + i + 4);
  bf16x8 o;
  o[0] = (bf16_t)v0.x; o[1] = (bf16_t)v0.y; o[2] = (bf16_t)v0.z; o[3] = (bf16_t)v0.w;
  o[4] = (bf16_t)v1.x; o[5] = (bf16_t)v1.y; o[6] = (bf16_t)v1.z; o[7] = (bf16_t)v1.w;
  *(bf16x8*)(out + i) = o;
}

__global__ __launch_bounds__(256) void cvt2(const float* __restrict__ inA,
                                            const float* __restrict__ inV,
                                            bf16_t* __restrict__ oA,
                                            bf16_t* __restrict__ oV) {
  const float* in = blockIdx.y ? inV : inA;
  bf16_t* out = blockIdx.y ? oV : oA;
  cvt8(in, out, (blockIdx.x * 256 + threadIdx.x) * 8);
}

__global__ __launch_bounds__(256) void cvt4(const float* __restrict__ i0, const float* __restrict__ i1,
                                            const float* __restrict__ i2, const float* __restrict__ i3,
                                            bf16_t* __restrict__ o0, bf16_t* __restrict__ o1,
                                            bf16_t* __restrict__ o2, bf16_t* __restrict__ o3) {
  const int z = blockIdx.y;
  const float* in = (z == 0) ? i0 : (z == 1) ? i1 : (z == 2) ? i2 : i3;
  bf16_t* out = (z == 0) ? o0 : (z == 1) ? o1 : (z == 2) ? o2 : o3;
  cvt8(in, out, (blockIdx.x * 256 + threadIdx.x) * 8);
}

// ---------------- row softmax: f32 [rows][4096] -> bf16 alpha ----------------
__global__ __launch_bounds__(256) void softmax_rows(const float* __restrict__ S,
                                                    bf16_t* __restrict__ P) {
  const int row = blockIdx.x;
  const int ncol = 4096;
  const float* s = S + (size_t)row * ncol;
  const int base = threadIdx.x * 16;
  float v[16];
  float4* vp = (float4*)v;
#pragma unroll
  for (int q = 0; q < 4; ++q) vp[q] = *(const float4*)(s + base + q * 4);
  float m = v[0];
#pragma unroll
  for (int q = 1; q < 16; ++q) m = fmaxf(m, v[q]);
  for (int off = 32; off; off >>= 1) m = fmaxf(m, __shfl_xor(m, off));
  __shared__ float sm[4], ss[4];
  const int wid = threadIdx.x >> 6, lane = threadIdx.x & 63;
  if (lane == 0) sm[wid] = m;
  __syncthreads();
  m = fmaxf(fmaxf(sm[0], sm[1]), fmaxf(sm[2], sm[3]));
  float sum = 0.f;
#pragma unroll
  for (int q = 0; q < 16; ++q) { v[q] = __expf(v[q] - m); sum += v[q]; }
  for (int off = 32; off; off >>= 1) sum += __shfl_xor(sum, off);
  if (lane == 0) ss[wid] = sum;
  __syncthreads();
  const float inv = 1.0f / (ss[0] + ss[1] + ss[2] + ss[3]);
  bf16x8 o0, o1;
#pragma unroll
  for (int q = 0; q < 8; ++q) { o0[q] = (bf16_t)(v[q] * inv); o1[q] = (bf16_t)(v[q + 8] * inv); }
  bf16_t* p = P + (size_t)row * ncol + base;
  *(bf16x8*)p = o0;
  *(bf16x8*)(p + 8) = o1;
}

// ---------------- bf16 transpose: in[R][C] -> out[C][R], 64x64 LDS tiles ----------------
__global__ __launch_bounds__(256) void transpose_bf16(const bf16_t* __restrict__ in,
                                                      bf16_t* __restrict__ out, int R, int C) {
  __shared__ bf16_t t[64][72];
  const int bx = blockIdx.x * 64;
  const int by = blockIdx.y * 64;
  const int tid = threadIdx.x;
  const int c8 = (tid & 7) * 8;
  const int r = tid >> 3;
#pragma unroll
  for (int rr = 0; rr < 64; rr += 32) {
    bf16x8 v = *(const bf16x8*)(in + (size_t)(by + r + rr) * C + bx + c8);
    *(bf16x8*)&t[r + rr][c8] = v;
  }
  __syncthreads();
#pragma unroll
  for (int rr = 0; rr < 64; rr += 32) {
    bf16x8 v;
#pragma unroll
    for (int q = 0; q < 8; ++q) v[q] = t[c8 + q][r + rr];
    *(bf16x8*)(out + (size_t)(bx + r + rr) * R + by + c8) = v;
  }
}

extern "C" void kernel_launch(void* const* d_in, const int* in_sizes, int n_in,
                              void* d_out, int out_size, void* d_ws, size_t ws_size,
                              hipStream_t stream) {
  (void)in_sizes; (void)n_in; (void)out_size; (void)ws_size;
  const float* inA = (const float*)d_in[0];
  const float* inV = (const float*)d_in[1];
  const float* wBa = (const float*)d_in[2];
  const float* wAa = (const float*)d_in[3];
  const float* wBv = (const float*)d_in[4];
  const float* wAv = (const float*)d_in[5];
  float* out = (float*)d_out;

  // workspace layout (~170 MB)
  char* w = (char*)d_ws;
  auto take = [&](size_t bytes) { void* p = (void*)w; w += bytes; return p; };
  const size_t XB = (size_t)NA_DIM * D_DIM * 2;   // 8 MB
  const size_t WB = (size_t)D_DIM * D_DIM * 2;    // 2 MB
  bf16_t* XaB = (bf16_t*)take(XB);
  bf16_t* XvB = (bf16_t*)take(XB);
  bf16_t* WBaB = (bf16_t*)take(WB);
  bf16_t* WAaB = (bf16_t*)take(WB);
  bf16_t* WBvB = (bf16_t*)take(WB);
  bf16_t* WAvB = (bf16_t*)take(WB);
  bf16_t* b_a = (bf16_t*)take(XB);
  bf16_t* a_v = (bf16_t*)take(XB);
  bf16_t* a_aT = (bf16_t*)take(XB);   // [1024][4096], written directly by proj4 z=1
  bf16_t* b_vT = (bf16_t*)take(XB);   // [1024][4096], written directly by proj4 z=3
  float* scores = (float*)take((size_t)NA_DIM * NV_DIM * 4);   // 64 MB
  bf16_t* alpha = (bf16_t*)take((size_t)NA_DIM * NV_DIM * 2);  // 32 MB
  bf16_t* alphaT = (bf16_t*)take((size_t)NA_DIM * NV_DIM * 2); // 32 MB

  // converts
  cvt2<<<dim3(NA_DIM * D_DIM / 2048, 2), 256, 0, stream>>>(inA, inV, XaB, XvB);
  cvt4<<<dim3(D_DIM * D_DIM / 2048, 4), 256, 0, stream>>>(wBa, wAa, wAv, wBv,
                                                          WBaB, WAaB, WAvB, WBvB);

  // stage 1: 4 projections; z=1 -> a_aT (transposed store), z=3 -> b_vT (transposed)
  gemm_proj4<<<dim3(NA_DIM / 256, D_DIM / 256, 4), 512, 0, stream>>>(
      XaB, XvB, WBaB, WAaB, WAvB, WBvB, b_a, a_aT, a_v, b_vT);

  // stage 2: scores[i][j] = sum_k b_a[i][k] * a_v[j][k]
  gemm_scores<<<dim3(NA_DIM / 256, NV_DIM / 256), 512, 0, stream>>>(b_a, a_v, scores);

  // stage 3: row softmax -> bf16 alpha
  softmax_rows<<<NA_DIM, 256, 0, stream>>>(scores, alpha);

  // alpha transpose (only remaining transpose)
  transpose_bf16<<<dim3(NV_DIM / 64, NA_DIM / 64), 256, 0, stream>>>(alpha, alphaT, NA_DIM, NV_DIM);

  // stages 4+5: 128x256-tile full-K GEMMs, residual fused (256 blocks, no reduce pass)
  gemm_att<<<dim3(NA_DIM / 128, D_DIM / 256, 2), 512, 0, stream>>>(
      alpha, b_vT, alphaT, a_aT, inA, inV, out);
}